// Round 5
// baseline (321.333 us; speedup 1.0000x reference)
//
#include <hip/hip_runtime.h>
#include <math.h>

#define T_FRAMES 16384
#define FDIM 2048
#define LQ 30
#define CHK 128            // k-floats per chunk
#define NCHK (FDIM / CHK)  // 16
#define FT 64              // frames per feas block
#define BF 64              // frames per attn block

// ---------------------------------------------------------------------------
// Kernel 0: precompute per-head 7x7 bilinear forms (unchanged)
// ---------------------------------------------------------------------------
__global__ __launch_bounds__(448) void setup_kernel(
    const float* __restrict__ Wq, const float* __restrict__ Wk,
    const float* __restrict__ Wv, const float* __restrict__ Wo,
    float* __restrict__ AM) {
  const int e = threadIdx.x;
  if (e >= 392) return;
  const int which = e / 196;
  const int r = e % 196;
  const int h = r / 49;
  const int rr = r % 49;
  const int c = rr / 7;
  const int c2 = rr % 7;
  float s = 0.0f;
  if (which == 0) {
    for (int d = 0; d < 64; ++d)
      s = fmaf(Wq[(h * 64 + d) * 7 + c], Wk[(h * 64 + d) * 7 + c2], s);
  } else {
    for (int d = 0; d < 64; ++d)
      s = fmaf(Wo[c * 256 + h * 64 + d], Wv[(h * 64 + d) * 7 + c2], s);
  }
  AM[e] = s;
}

// ---------------------------------------------------------------------------
// Kernel 1 (v6): feas = tanh(lf . Wfc^T), continuous-stream pipeline.
// 256 blocks x 256 thr; block owns 64 frames; 16 K-chunks of 128 floats.
// Pipeline per iter ch: issue global loads for chunk ch+2 (into the reg
// bank freed last iter) -> compute chunk ch from LDS -> ds_write chunk ch+1
// (compiler's auto-vmcnt waits only the older load group) -> barrier.
// Compute maps lane->frame (XOR-swizzled LDS, write side matched): acc[7]
// is thread-private, NO cross-lane shuffles. Wfc addresses wave-uniform
// (readfirstlane) -> scalar loads.
// ---------------------------------------------------------------------------
__global__ __launch_bounds__(256) void feas_kernel(
    const float* __restrict__ lf,    // (T, 2048)
    const float* __restrict__ Wfc,   // (7, 2048)
    float* __restrict__ feas) {      // (T, 7)
  __shared__ float lfs[2][FT * CHK];   // 2 x 32 KB
  __shared__ float red[4][FT * 7];     // 7 KB

  const int tid = threadIdx.x;
  const int f   = tid & 63;            // frame lane (compute)
  const int q   = tid >> 6;            // k-quarter = wave id
  const int t0  = blockIdx.x * FT;
  const float* lfbase = lf + (size_t)t0 * FDIM;

  // staging map: id i = p*256+tid -> row r=i>>5, granule g=i&31 (granule=16B)
  int gofs[8];  // global float offset (row r, granule g), chunk 0
  int lofs[8];  // LDS float offset (swizzled), per buffer
#pragma unroll
  for (int p = 0; p < 8; ++p) {
    const int i = p * 256 + tid, r = i >> 5, g = i & 31;
    gofs[p] = r * FDIM + g * 4;
    lofs[p] = r * CHK + (((g * 16) ^ ((r & 31) << 4)) >> 2);
  }
  // compute-read map: granule x = q*8+j of row f, same swizzle
  int rofs[8];
#pragma unroll
  for (int j = 0; j < 8; ++j) {
    const int x = q * 8 + j;
    rofs[j] = f * CHK + ((((x * 16)) ^ ((f & 31) << 4)) >> 2);
  }

  const int qk = __builtin_amdgcn_readfirstlane(q) * 32;  // scalar k-base

  float4 bankA[8], bankB[8];

  // ---- prologue: stage chunk 0, issue chunk 1 ----
#pragma unroll
  for (int p = 0; p < 8; ++p) bankA[p] = *(const float4*)(lfbase + gofs[p]);
#pragma unroll
  for (int p = 0; p < 8; ++p) *(float4*)(&lfs[0][lofs[p]]) = bankA[p];
#pragma unroll
  for (int p = 0; p < 8; ++p) bankB[p] = *(const float4*)(lfbase + gofs[p] + CHK);
  __syncthreads();

  float acc[7] = {0, 0, 0, 0, 0, 0, 0};

#define COMPUTE_CHUNK(PB, CH)                                                  \
  {                                                                            \
    float4 a[8];                                                               \
    _Pragma("unroll") for (int j = 0; j < 8; ++j)                              \
        a[j] = *(const float4*)(&lfs[PB][rofs[j]]);                            \
    const float* wrow = Wfc + (CH) * CHK + qk;                                 \
    _Pragma("unroll") for (int c = 0; c < 7; ++c) {                            \
      const float4* wp = (const float4*)(wrow + c * FDIM);                     \
      _Pragma("unroll") for (int j = 0; j < 8; ++j) {                          \
        const float4 w = wp[j];                                                \
        acc[c] = fmaf(a[j].x, w.x, fmaf(a[j].y, w.y,                           \
                 fmaf(a[j].z, w.z, fmaf(a[j].w, w.w, acc[c]))));               \
      }                                                                        \
    }                                                                          \
  }

  for (int ch2 = 0; ch2 < NCHK / 2; ++ch2) {
    const int ch = ch2 * 2;
    const bool more = (ch2 < NCHK / 2 - 1);
    // ---- even iter: refill A<-ch+2, compute lfs0 (=ch), write lfs1<-B (=ch+1)
    if (more) {
#pragma unroll
      for (int p = 0; p < 8; ++p)
        bankA[p] = *(const float4*)(lfbase + gofs[p] + (ch + 2) * CHK);
    }
    COMPUTE_CHUNK(0, ch)
#pragma unroll
    for (int p = 0; p < 8; ++p) *(float4*)(&lfs[1][lofs[p]]) = bankB[p];
    __syncthreads();
    // ---- odd iter: refill B<-ch+3, compute lfs1 (=ch+1), write lfs0<-A (=ch+2)
    if (more) {
#pragma unroll
      for (int p = 0; p < 8; ++p)
        bankB[p] = *(const float4*)(lfbase + gofs[p] + (ch + 3) * CHK);
    }
    COMPUTE_CHUNK(1, ch + 1)
    if (more) {
#pragma unroll
      for (int p = 0; p < 8; ++p) *(float4*)(&lfs[0][lofs[p]]) = bankA[p];
    }
    __syncthreads();
  }

  // ---- cross-quarter reduce (4 partials per (f,c)), tanh, store ----
#pragma unroll
  for (int c = 0; c < 7; ++c) red[q][f * 7 + c] = acc[c];
  __syncthreads();
  for (int j = tid; j < FT * 7; j += 256) {
    const float s = red[0][j] + red[1][j] + red[2][j] + red[3][j];
    feas[(size_t)t0 * 7 + j] = tanhf(s);
  }
}

// ---------------------------------------------------------------------------
// Kernel 2: attention + FFN + LNs (unchanged -- verified, cheap).
// ---------------------------------------------------------------------------
__global__ __launch_bounds__(256) void attn_kernel(
    const float* __restrict__ x,       // (7, T)
    const float* __restrict__ feas_g,  // (T, 7)  == out
    const float* __restrict__ AM,      // 392
    const float* __restrict__ W1,      // (64, 7)
    const float* __restrict__ W2,      // (7, 64)
    const float* __restrict__ ln1g, const float* __restrict__ ln1b,
    const float* __restrict__ ln2g, const float* __restrict__ ln2b,
    float* __restrict__ out) {         // (T, 7)
  __shared__ float AM_s[392];
  __shared__ float ft[(BF + LQ - 1) * 7];
  __shared__ float feas_s[BF][7];
  __shared__ float hpart[BF][4][7];

  const int tid = threadIdx.x;
  const int t0 = blockIdx.x * BF;

  for (int i = tid; i < 392; i += 256) AM_s[i] = AM[i];
  for (int i = tid; i < (BF + LQ - 1) * 7; i += 256) {
    const int row = i / 7, c = i % 7;
    const int s = t0 - (LQ - 1) + row;
    ft[i] = (s >= 0) ? x[c * T_FRAMES + s] : 0.0f;
  }
  for (int i = tid; i < BF * 7; i += 256)
    feas_s[i / 7][i % 7] = feas_g[(size_t)t0 * 7 + i];
  __syncthreads();

  // ---- phase 2a: (frame, head) per thread, 256/256 active ----
  {
    const int f = tid >> 2;
    const int h = tid & 3;
    float fe[7];
#pragma unroll
    for (int c = 0; c < 7; ++c) fe[c] = feas_s[f][c];

    const float* Ah = AM_s + h * 49;
    const float* Mh = AM_s + 196 + h * 49;
    float qk[7];
#pragma unroll
    for (int c2 = 0; c2 < 7; ++c2) {
      float s = 0.0f;
#pragma unroll
      for (int c = 0; c < 7; ++c) s = fmaf(fe[c], Ah[c * 7 + c2], s);
      qk[c2] = s * 0.125f;
    }
    const float* frow = &ft[f * 7];
    float sc[LQ];
    float m = -1e30f;
#pragma unroll
    for (int j = 0; j < LQ; ++j) {
      const float* r = frow + j * 7;
      float s = 0.0f;
#pragma unroll
      for (int c2 = 0; c2 < 7; ++c2) s = fmaf(qk[c2], r[c2], s);
      sc[j] = s;
      m = fmaxf(m, s);
    }
    float sum = 0.0f;
    float wsum[7] = {0, 0, 0, 0, 0, 0, 0};
#pragma unroll
    for (int j = 0; j < LQ; ++j) {
      const float p = __expf(sc[j] - m);
      sum += p;
      const float* r = frow + j * 7;
#pragma unroll
      for (int c2 = 0; c2 < 7; ++c2) wsum[c2] = fmaf(p, r[c2], wsum[c2]);
    }
    const float inv = 1.0f / sum;
#pragma unroll
    for (int c = 0; c < 7; ++c) {
      float s = 0.0f;
#pragma unroll
      for (int c2 = 0; c2 < 7; ++c2) s = fmaf(Mh[c * 7 + c2], wsum[c2], s);
      hpart[f][h][c] = s * inv;
    }
  }
  __syncthreads();

  // ---- phase 2b: per-frame epilogue ----
  if (tid < BF) {
    const int f = tid;
    float v[7];
#pragma unroll
    for (int c = 0; c < 7; ++c)
      v[c] = feas_s[f][c] + hpart[f][0][c] + hpart[f][1][c] + hpart[f][2][c] + hpart[f][3][c];

    float mu = 0.0f;
#pragma unroll
    for (int c = 0; c < 7; ++c) mu += v[c];
    mu *= (1.0f / 7.0f);
    float var = 0.0f;
#pragma unroll
    for (int c = 0; c < 7; ++c) { const float d = v[c] - mu; var = fmaf(d, d, var); }
    var *= (1.0f / 7.0f);
    float rs = rsqrtf(var + 1e-5f);
    float o1[7];
#pragma unroll
    for (int c = 0; c < 7; ++c) o1[c] = (v[c] - mu) * rs * ln1g[c] + ln1b[c];

    float ff[7] = {0, 0, 0, 0, 0, 0, 0};
    for (int k = 0; k < 64; ++k) {
      float hk = 0.0f;
#pragma unroll
      for (int c = 0; c < 7; ++c) hk = fmaf(W1[k * 7 + c], o1[c], hk);
      hk = fmaxf(hk, 0.0f);
#pragma unroll
      for (int c = 0; c < 7; ++c) ff[c] = fmaf(W2[c * 64 + k], hk, ff[c]);
    }

#pragma unroll
    for (int c = 0; c < 7; ++c) v[c] = ff[c] + o1[c];
    mu = 0.0f;
#pragma unroll
    for (int c = 0; c < 7; ++c) mu += v[c];
    mu *= (1.0f / 7.0f);
    var = 0.0f;
#pragma unroll
    for (int c = 0; c < 7; ++c) { const float d = v[c] - mu; var = fmaf(d, d, var); }
    var *= (1.0f / 7.0f);
    rs = rsqrtf(var + 1e-5f);
    const int t = t0 + f;
#pragma unroll
    for (int c = 0; c < 7; ++c)
      out[(size_t)t * 7 + c] = (v[c] - mu) * rs * ln2g[c] + ln2b[c];
  }
}

// ---------------------------------------------------------------------------
extern "C" void kernel_launch(void* const* d_in, const int* in_sizes, int n_in,
                              void* d_out, int out_size, void* d_ws, size_t ws_size,
                              hipStream_t stream) {
  const float* x    = (const float*)d_in[0];   // (1, 7, T)
  const float* lf   = (const float*)d_in[1];   // (1, T, 2048)
  const float* Wfc  = (const float*)d_in[2];   // (7, 2048)
  const float* Wq   = (const float*)d_in[3];   // (256, 7)
  const float* Wk   = (const float*)d_in[4];   // (256, 7)
  const float* Wv   = (const float*)d_in[5];   // (256, 7)
  const float* Wo   = (const float*)d_in[6];   // (7, 256)
  const float* ln1g = (const float*)d_in[7];
  const float* ln1b = (const float*)d_in[8];
  const float* W1   = (const float*)d_in[9];   // (64, 7)
  const float* W2   = (const float*)d_in[10];  // (7, 64)
  const float* ln2g = (const float*)d_in[11];
  const float* ln2b = (const float*)d_in[12];
  float* out = (float*)d_out;

  float* AM = (float*)d_ws;   // 392 floats

  setup_kernel<<<1, 448, 0, stream>>>(Wq, Wk, Wv, Wo, AM);
  // feas written into `out` (scratch); attn_kernel rewrites it in place.
  feas_kernel<<<T_FRAMES / FT, 256, 0, stream>>>(lf, Wfc, out);
  attn_kernel<<<T_FRAMES / BF, 256, 0, stream>>>(
      x, out, AM, W1, W2, ln1g, ln1b, ln2g, ln2b, out);
}

// Round 6
// 250.156 us; speedup vs baseline: 1.2845x; 1.2845x over previous
//
#include <hip/hip_runtime.h>
#include <math.h>

#define T_FRAMES 16384
#define FDIM 2048
#define LQ 30
#define FB 32         // frames per feas block
#define BF 64         // frames per attn block

// ---------------------------------------------------------------------------
// Kernel 0: precompute per-head 7x7 bilinear forms (unchanged)
// ---------------------------------------------------------------------------
__global__ __launch_bounds__(448) void setup_kernel(
    const float* __restrict__ Wq, const float* __restrict__ Wk,
    const float* __restrict__ Wv, const float* __restrict__ Wo,
    float* __restrict__ AM) {
  const int e = threadIdx.x;
  if (e >= 392) return;
  const int which = e / 196;
  const int r = e % 196;
  const int h = r / 49;
  const int rr = r % 49;
  const int c = rr / 7;
  const int c2 = rr % 7;
  float s = 0.0f;
  if (which == 0) {
    for (int d = 0; d < 64; ++d)
      s = fmaf(Wq[(h * 64 + d) * 7 + c], Wk[(h * 64 + d) * 7 + c2], s);
  } else {
    for (int d = 0; d < 64; ++d)
      s = fmaf(Wo[c * 256 + h * 64 + d], Wv[(h * 64 + d) * 7 + c2], s);
  }
  AM[e] = s;
}

// ---------------------------------------------------------------------------
// Kernel 1 (v7): feas = tanh(lf . Wfc^T) -- BARRIER-FREE CONTINUOUS STREAM.
// Diagnosis of v0-v6: every design alternated load-burst -> drain ->
// dependent reduce/barrier, so avg outstanding bytes/CU was ~2 KB and
// effective read BW pinned at ~1.6 TB/s regardless of occupancy.
// Here: lane = frame. Each lane streams its own 8 KB row segment with
// sequential float4 loads (unroll x4 => ~4 loads in flight per lane,
// ~32 KB outstanding per CU, no drain until the row segment ends).
// NO shuffles, NO barriers in the stream loop. Wfc sits in LDS and is
// read as same-address broadcast per half-wave (2 addrs/wave: free).
// One __shfl_xor(32) + tiny LDS reduce at the very end.
//   block: 256 thr / 4 waves; 32 frames; wave q -> k in [q*512,(q+1)*512),
//   half h -> 256-float k-half; lane&31 -> frame. grid 512 = 2 blocks/CU.
// ---------------------------------------------------------------------------
__global__ __launch_bounds__(256) void feas_kernel(
    const float* __restrict__ lf,    // (T, 2048)
    const float* __restrict__ Wfc,   // (7, 2048)
    float* __restrict__ feas) {      // (T, 7)
  __shared__ float wfc_s[7 * FDIM];   // 56 KB
  __shared__ float red[4][FB * 7];    // 3.5 KB

  const int tid  = threadIdx.x;
  const int lane = tid & 63;
  const int wave = tid >> 6;          // k-slice of 512 floats
  const int half = lane >> 5;         // k-half of 256 floats
  const int f    = lane & 31;         // frame within block
  const int t0   = blockIdx.x * FB;

  // ---- stage Wfc once (3584 float4, coalesced, 14 per thread) ----
  {
    const float4* src = (const float4*)Wfc;
    float4* dst = (float4*)wfc_s;
#pragma unroll
    for (int i = 0; i < 14; ++i) dst[tid + i * 256] = src[tid + i * 256];
  }
  __syncthreads();

  const int kb = wave * 512 + half * 256;          // this lane's k-base
  const float* rowp  = lf + (size_t)(t0 + f) * FDIM + kb;
  const float* wbase = wfc_s + kb;

  float acc[7] = {0, 0, 0, 0, 0, 0, 0};

  // ---- stream loop: 64 float4 steps, no barriers, loads 4-deep ----
  for (int j = 0; j < 64; j += 4) {
    const float4 a0 = *(const float4*)(rowp + j * 4);
    const float4 a1 = *(const float4*)(rowp + j * 4 + 4);
    const float4 a2 = *(const float4*)(rowp + j * 4 + 8);
    const float4 a3 = *(const float4*)(rowp + j * 4 + 12);
#pragma unroll
    for (int c = 0; c < 7; ++c) {
      const float* wc = wbase + c * FDIM + j * 4;
      const float4 w0 = *(const float4*)(wc);
      const float4 w1 = *(const float4*)(wc + 4);
      const float4 w2 = *(const float4*)(wc + 8);
      const float4 w3 = *(const float4*)(wc + 12);
      acc[c] = fmaf(a0.x, w0.x, fmaf(a0.y, w0.y,
               fmaf(a0.z, w0.z, fmaf(a0.w, w0.w, acc[c]))));
      acc[c] = fmaf(a1.x, w1.x, fmaf(a1.y, w1.y,
               fmaf(a1.z, w1.z, fmaf(a1.w, w1.w, acc[c]))));
      acc[c] = fmaf(a2.x, w2.x, fmaf(a2.y, w2.y,
               fmaf(a2.z, w2.z, fmaf(a2.w, w2.w, acc[c]))));
      acc[c] = fmaf(a3.x, w3.x, fmaf(a3.y, w3.y,
               fmaf(a3.z, w3.z, fmaf(a3.w, w3.w, acc[c]))));
    }
  }

  // ---- combine the two k-halves (single xor-shuffle per channel) ----
#pragma unroll
  for (int c = 0; c < 7; ++c) acc[c] += __shfl_xor(acc[c], 32, 64);

  if (lane < 32) {
#pragma unroll
    for (int c = 0; c < 7; ++c) red[wave][f * 7 + c] = acc[c];
  }
  __syncthreads();

  // ---- cross-wave sum (4 k-slices) + tanh + contiguous store ----
  for (int j = tid; j < FB * 7; j += 256) {
    const float s = red[0][j] + red[1][j] + red[2][j] + red[3][j];
    feas[(size_t)t0 * 7 + j] = tanhf(s);
  }
}

// ---------------------------------------------------------------------------
// Kernel 2: attention + FFN + LNs (unchanged -- verified, cheap).
// ---------------------------------------------------------------------------
__global__ __launch_bounds__(256) void attn_kernel(
    const float* __restrict__ x,       // (7, T)
    const float* __restrict__ feas_g,  // (T, 7)  == out
    const float* __restrict__ AM,      // 392
    const float* __restrict__ W1,      // (64, 7)
    const float* __restrict__ W2,      // (7, 64)
    const float* __restrict__ ln1g, const float* __restrict__ ln1b,
    const float* __restrict__ ln2g, const float* __restrict__ ln2b,
    float* __restrict__ out) {         // (T, 7)
  __shared__ float AM_s[392];
  __shared__ float ft[(BF + LQ - 1) * 7];
  __shared__ float feas_s[BF][7];
  __shared__ float hpart[BF][4][7];

  const int tid = threadIdx.x;
  const int t0 = blockIdx.x * BF;

  for (int i = tid; i < 392; i += 256) AM_s[i] = AM[i];
  for (int i = tid; i < (BF + LQ - 1) * 7; i += 256) {
    const int row = i / 7, c = i % 7;
    const int s = t0 - (LQ - 1) + row;
    ft[i] = (s >= 0) ? x[c * T_FRAMES + s] : 0.0f;
  }
  for (int i = tid; i < BF * 7; i += 256)
    feas_s[i / 7][i % 7] = feas_g[(size_t)t0 * 7 + i];
  __syncthreads();

  // ---- phase 2a: (frame, head) per thread, 256/256 active ----
  {
    const int f = tid >> 2;
    const int h = tid & 3;
    float fe[7];
#pragma unroll
    for (int c = 0; c < 7; ++c) fe[c] = feas_s[f][c];

    const float* Ah = AM_s + h * 49;
    const float* Mh = AM_s + 196 + h * 49;
    float qk[7];
#pragma unroll
    for (int c2 = 0; c2 < 7; ++c2) {
      float s = 0.0f;
#pragma unroll
      for (int c = 0; c < 7; ++c) s = fmaf(fe[c], Ah[c * 7 + c2], s);
      qk[c2] = s * 0.125f;
    }
    const float* frow = &ft[f * 7];
    float sc[LQ];
    float m = -1e30f;
#pragma unroll
    for (int j = 0; j < LQ; ++j) {
      const float* r = frow + j * 7;
      float s = 0.0f;
#pragma unroll
      for (int c2 = 0; c2 < 7; ++c2) s = fmaf(qk[c2], r[c2], s);
      sc[j] = s;
      m = fmaxf(m, s);
    }
    float sum = 0.0f;
    float wsum[7] = {0, 0, 0, 0, 0, 0, 0};
#pragma unroll
    for (int j = 0; j < LQ; ++j) {
      const float p = __expf(sc[j] - m);
      sum += p;
      const float* r = frow + j * 7;
#pragma unroll
      for (int c2 = 0; c2 < 7; ++c2) wsum[c2] = fmaf(p, r[c2], wsum[c2]);
    }
    const float inv = 1.0f / sum;
#pragma unroll
    for (int c = 0; c < 7; ++c) {
      float s = 0.0f;
#pragma unroll
      for (int c2 = 0; c2 < 7; ++c2) s = fmaf(Mh[c * 7 + c2], wsum[c2], s);
      hpart[f][h][c] = s * inv;
    }
  }
  __syncthreads();

  // ---- phase 2b: per-frame epilogue ----
  if (tid < BF) {
    const int f = tid;
    float v[7];
#pragma unroll
    for (int c = 0; c < 7; ++c)
      v[c] = feas_s[f][c] + hpart[f][0][c] + hpart[f][1][c] + hpart[f][2][c] + hpart[f][3][c];

    float mu = 0.0f;
#pragma unroll
    for (int c = 0; c < 7; ++c) mu += v[c];
    mu *= (1.0f / 7.0f);
    float var = 0.0f;
#pragma unroll
    for (int c = 0; c < 7; ++c) { const float d = v[c] - mu; var = fmaf(d, d, var); }
    var *= (1.0f / 7.0f);
    float rs = rsqrtf(var + 1e-5f);
    float o1[7];
#pragma unroll
    for (int c = 0; c < 7; ++c) o1[c] = (v[c] - mu) * rs * ln1g[c] + ln1b[c];

    float ff[7] = {0, 0, 0, 0, 0, 0, 0};
    for (int k = 0; k < 64; ++k) {
      float hk = 0.0f;
#pragma unroll
      for (int c = 0; c < 7; ++c) hk = fmaf(W1[k * 7 + c], o1[c], hk);
      hk = fmaxf(hk, 0.0f);
#pragma unroll
      for (int c = 0; c < 7; ++c) ff[c] = fmaf(W2[c * 64 + k], hk, ff[c]);
    }

#pragma unroll
    for (int c = 0; c < 7; ++c) v[c] = ff[c] + o1[c];
    mu = 0.0f;
#pragma unroll
    for (int c = 0; c < 7; ++c) mu += v[c];
    mu *= (1.0f / 7.0f);
    var = 0.0f;
#pragma unroll
    for (int c = 0; c < 7; ++c) { const float d = v[c] - mu; var = fmaf(d, d, var); }
    var *= (1.0f / 7.0f);
    rs = rsqrtf(var + 1e-5f);
    const int t = t0 + f;
#pragma unroll
    for (int c = 0; c < 7; ++c)
      out[(size_t)t * 7 + c] = (v[c] - mu) * rs * ln2g[c] + ln2b[c];
  }
}

// ---------------------------------------------------------------------------
extern "C" void kernel_launch(void* const* d_in, const int* in_sizes, int n_in,
                              void* d_out, int out_size, void* d_ws, size_t ws_size,
                              hipStream_t stream) {
  const float* x    = (const float*)d_in[0];   // (1, 7, T)
  const float* lf   = (const float*)d_in[1];   // (1, T, 2048)
  const float* Wfc  = (const float*)d_in[2];   // (7, 2048)
  const float* Wq   = (const float*)d_in[3];   // (256, 7)
  const float* Wk   = (const float*)d_in[4];   // (256, 7)
  const float* Wv   = (const float*)d_in[5];   // (256, 7)
  const float* Wo   = (const float*)d_in[6];   // (7, 256)
  const float* ln1g = (const float*)d_in[7];
  const float* ln1b = (const float*)d_in[8];
  const float* W1   = (const float*)d_in[9];   // (64, 7)
  const float* W2   = (const float*)d_in[10];  // (7, 64)
  const float* ln2g = (const float*)d_in[11];
  const float* ln2b = (const float*)d_in[12];
  float* out = (float*)d_out;

  float* AM = (float*)d_ws;   // 392 floats

  setup_kernel<<<1, 448, 0, stream>>>(Wq, Wk, Wv, Wo, AM);
  // feas written into `out` (scratch); attn_kernel rewrites it in place.
  feas_kernel<<<T_FRAMES / FB, 256, 0, stream>>>(lf, Wfc, out);
  attn_kernel<<<T_FRAMES / BF, 256, 0, stream>>>(
      x, out, AM, W1, W2, ln1g, ln1b, ln2g, ln2b, out);
}

// Round 7
// 244.963 us; speedup vs baseline: 1.3118x; 1.0212x over previous
//
#include <hip/hip_runtime.h>
#include <math.h>

#define T_FRAMES 16384
#define FDIM 2048
#define LQ 30
#define FB 32         // frames per feas block
#define BF 64         // frames per attn block

// ---------------------------------------------------------------------------
// Kernel 0: precompute per-head 7x7 bilinear forms (unchanged)
// AM layout: [0..195] = A (h*49 + c*7 + c2), [196..391] = M
// ---------------------------------------------------------------------------
__global__ __launch_bounds__(448) void setup_kernel(
    const float* __restrict__ Wq, const float* __restrict__ Wk,
    const float* __restrict__ Wv, const float* __restrict__ Wo,
    float* __restrict__ AM) {
  const int e = threadIdx.x;
  if (e >= 392) return;
  const int which = e / 196;
  const int r = e % 196;
  const int h = r / 49;
  const int rr = r % 49;
  const int c = rr / 7;
  const int c2 = rr % 7;
  float s = 0.0f;
  if (which == 0) {
    for (int d = 0; d < 64; ++d)
      s = fmaf(Wq[(h * 64 + d) * 7 + c], Wk[(h * 64 + d) * 7 + c2], s);
  } else {
    for (int d = 0; d < 64; ++d)
      s = fmaf(Wo[c * 256 + h * 64 + d], Wv[(h * 64 + d) * 7 + c2], s);
  }
  AM[e] = s;
}

// ---------------------------------------------------------------------------
// Kernel 0b: build bank-swizzled k-major Wfc in workspace.
// WT[k4*32 + slot]: slot = (c ^ (k4&7))*4 + e  holds Wfc[c][k4*4+e], c<7.
// Ghost channel (c==7) slots get 0. Row = 32 floats (128 B, float4-aligned);
// the XOR by k4&7 spreads the 16-lane strided read across 8 bank-quads
// (2-way conflict = free).
// ---------------------------------------------------------------------------
__global__ __launch_bounds__(1024) void wfct_kernel(
    const float* __restrict__ Wfc, float* __restrict__ WT) {
  const int i = blockIdx.x * 1024 + threadIdx.x;
  if (i >= 512 * 32) return;
  const int k4 = i >> 5, slot = i & 31;
  const int key = k4 & 7;
  const int c = (slot >> 2) ^ key;
  const int e = slot & 3;
  WT[i] = (c < 7) ? Wfc[c * FDIM + k4 * 4 + e] : 0.0f;
}

// ---------------------------------------------------------------------------
// Kernel 1 (v9): feas = tanh(lf . Wfc^T)
// Coalesced + 16-lane-local reduce + swizzled k-major weights in LDS.
//  - wave = 4 frames (fs = lane>>4); 16 lanes sweep the 2048-float row in
//    32 j-steps: load = 4 x 256B segments per instruction (coalesced per
//    frame-group), 1 global float4 + 7 conflict-free ds_read_b128 + 28 FMA.
//  - unroll 4 -> >=4 global loads in flight per lane, ~55 live VGPR.
//  - reduction: 4-step __shfl_xor width=16 (7 per frame, not 42).
//  - LDS: WT 64 KB (L2-hot, all blocks read same bytes) + red 0.9 KB
//    -> 2 blocks/CU, 8 waves/CU.
// ---------------------------------------------------------------------------
__global__ __launch_bounds__(256) void feas_kernel(
    const float* __restrict__ lf,    // (T, 2048)
    const float* __restrict__ WT,    // 512*32 swizzled k-major Wfc
    float* __restrict__ feas) {      // (T, 7)
  __shared__ float wt[512 * 32];     // 64 KB
  __shared__ float red[8][4][7];     // [quad][fs][c] == frame-major

  const int tid  = threadIdx.x;
  const int lane = tid & 63;
  const int wave = tid >> 6;
  const int t0   = blockIdx.x * FB;

  // stage WT (4096 float4, coalesced, 16/thread; L2-hot after first touch)
  {
    const float4* s = (const float4*)WT;
    float4* d = (float4*)wt;
#pragma unroll
    for (int i = 0; i < 16; ++i) d[tid + i * 256] = s[tid + i * 256];
  }
  __syncthreads();

  const int fs  = lane >> 4;         // frame-sub within wave
  const int l16 = lane & 15;         // k-lane within frame group
  const int key = l16 & 7;           // == k4&7 for all j (j*16 ≡ 0 mod 8)

  for (int qi = 0; qi < 2; ++qi) {
    const int q = wave + qi * 4;     // quad id 0..7
    const float* rowp = lf + (size_t)(t0 + q * 4 + fs) * FDIM;

    float acc[7] = {0, 0, 0, 0, 0, 0, 0};
#pragma unroll 4
    for (int j = 0; j < 32; ++j) {
      const float4 a = *(const float4*)(rowp + j * 64 + l16 * 4);
      const float* wbase = wt + (j * 16 + l16) * 32;
#pragma unroll
      for (int c = 0; c < 7; ++c) {
        const float4 w = *(const float4*)(wbase + ((c ^ key) << 2));
        acc[c] = fmaf(a.x, w.x, fmaf(a.y, w.y,
                 fmaf(a.z, w.z, fmaf(a.w, w.w, acc[c]))));
      }
    }

    // 16-lane butterfly: every lane of the group ends with the frame's sums
#pragma unroll
    for (int c = 0; c < 7; ++c) {
      acc[c] += __shfl_xor(acc[c], 1, 16);
      acc[c] += __shfl_xor(acc[c], 2, 16);
      acc[c] += __shfl_xor(acc[c], 4, 16);
      acc[c] += __shfl_xor(acc[c], 8, 16);
    }
    // lane l16 < 7 publishes channel l16 (static select chain, no dyn index)
    float v = acc[0];
#pragma unroll
    for (int c = 1; c < 7; ++c)
      if (l16 == c) v = acc[c];
    if (l16 < 7) red[q][fs][l16] = v;
  }
  __syncthreads();

  // red is frame-major: flat[i] = frame (t0+i/7), channel i%7
  if (tid < FB * 7)
    feas[(size_t)t0 * 7 + tid] = tanhf(((const float*)red)[tid]);
}

// ---------------------------------------------------------------------------
// Kernel 2: attention + FFN + LNs (unchanged -- verified, cheap).
// ---------------------------------------------------------------------------
__global__ __launch_bounds__(256) void attn_kernel(
    const float* __restrict__ x,       // (7, T)
    const float* __restrict__ feas_g,  // (T, 7)  == out
    const float* __restrict__ AM,      // 392
    const float* __restrict__ W1,      // (64, 7)
    const float* __restrict__ W2,      // (7, 64)
    const float* __restrict__ ln1g, const float* __restrict__ ln1b,
    const float* __restrict__ ln2g, const float* __restrict__ ln2b,
    float* __restrict__ out) {         // (T, 7)
  __shared__ float AM_s[392];
  __shared__ float ft[(BF + LQ - 1) * 7];
  __shared__ float feas_s[BF][7];
  __shared__ float hpart[BF][4][7];

  const int tid = threadIdx.x;
  const int t0 = blockIdx.x * BF;

  for (int i = tid; i < 392; i += 256) AM_s[i] = AM[i];
  for (int i = tid; i < (BF + LQ - 1) * 7; i += 256) {
    const int row = i / 7, c = i % 7;
    const int s = t0 - (LQ - 1) + row;
    ft[i] = (s >= 0) ? x[c * T_FRAMES + s] : 0.0f;
  }
  for (int i = tid; i < BF * 7; i += 256)
    feas_s[i / 7][i % 7] = feas_g[(size_t)t0 * 7 + i];
  __syncthreads();

  // ---- phase 2a: (frame, head) per thread, 256/256 active ----
  {
    const int f = tid >> 2;
    const int h = tid & 3;
    float fe[7];
#pragma unroll
    for (int c = 0; c < 7; ++c) fe[c] = feas_s[f][c];

    const float* Ah = AM_s + h * 49;
    const float* Mh = AM_s + 196 + h * 49;
    float qk[7];
#pragma unroll
    for (int c2 = 0; c2 < 7; ++c2) {
      float s = 0.0f;
#pragma unroll
      for (int c = 0; c < 7; ++c) s = fmaf(fe[c], Ah[c * 7 + c2], s);
      qk[c2] = s * 0.125f;
    }
    const float* frow = &ft[f * 7];
    float sc[LQ];
    float m = -1e30f;
#pragma unroll
    for (int j = 0; j < LQ; ++j) {
      const float* r = frow + j * 7;
      float s = 0.0f;
#pragma unroll
      for (int c2 = 0; c2 < 7; ++c2) s = fmaf(qk[c2], r[c2], s);
      sc[j] = s;
      m = fmaxf(m, s);
    }
    float sum = 0.0f;
    float wsum[7] = {0, 0, 0, 0, 0, 0, 0};
#pragma unroll
    for (int j = 0; j < LQ; ++j) {
      const float p = __expf(sc[j] - m);
      sum += p;
      const float* r = frow + j * 7;
#pragma unroll
      for (int c2 = 0; c2 < 7; ++c2) wsum[c2] = fmaf(p, r[c2], wsum[c2]);
    }
    const float inv = 1.0f / sum;
#pragma unroll
    for (int c = 0; c < 7; ++c) {
      float s = 0.0f;
#pragma unroll
      for (int c2 = 0; c2 < 7; ++c2) s = fmaf(Mh[c * 7 + c2], wsum[c2], s);
      hpart[f][h][c] = s * inv;
    }
  }
  __syncthreads();

  // ---- phase 2b: per-frame epilogue ----
  if (tid < BF) {
    const int f = tid;
    float v[7];
#pragma unroll
    for (int c = 0; c < 7; ++c)
      v[c] = feas_s[f][c] + hpart[f][0][c] + hpart[f][1][c] + hpart[f][2][c] + hpart[f][3][c];

    float mu = 0.0f;
#pragma unroll
    for (int c = 0; c < 7; ++c) mu += v[c];
    mu *= (1.0f / 7.0f);
    float var = 0.0f;
#pragma unroll
    for (int c = 0; c < 7; ++c) { const float d = v[c] - mu; var = fmaf(d, d, var); }
    var *= (1.0f / 7.0f);
    float rs = rsqrtf(var + 1e-5f);
    float o1[7];
#pragma unroll
    for (int c = 0; c < 7; ++c) o1[c] = (v[c] - mu) * rs * ln1g[c] + ln1b[c];

    float ff[7] = {0, 0, 0, 0, 0, 0, 0};
    for (int k = 0; k < 64; ++k) {
      float hk = 0.0f;
#pragma unroll
      for (int c = 0; c < 7; ++c) hk = fmaf(W1[k * 7 + c], o1[c], hk);
      hk = fmaxf(hk, 0.0f);
#pragma unroll
      for (int c = 0; c < 7; ++c) ff[c] = fmaf(W2[c * 64 + k], hk, ff[c]);
    }

#pragma unroll
    for (int c = 0; c < 7; ++c) v[c] = ff[c] + o1[c];
    mu = 0.0f;
#pragma unroll
    for (int c = 0; c < 7; ++c) mu += v[c];
    mu *= (1.0f / 7.0f);
    var = 0.0f;
#pragma unroll
    for (int c = 0; c < 7; ++c) { const float d = v[c] - mu; var = fmaf(d, d, var); }
    var *= (1.0f / 7.0f);
    rs = rsqrtf(var + 1e-5f);
    const int t = t0 + f;
#pragma unroll
    for (int c = 0; c < 7; ++c)
      out[(size_t)t * 7 + c] = (v[c] - mu) * rs * ln2g[c] + ln2b[c];
  }
}

// ---------------------------------------------------------------------------
extern "C" void kernel_launch(void* const* d_in, const int* in_sizes, int n_in,
                              void* d_out, int out_size, void* d_ws, size_t ws_size,
                              hipStream_t stream) {
  const float* x    = (const float*)d_in[0];   // (1, 7, T)
  const float* lf   = (const float*)d_in[1];   // (1, T, 2048)
  const float* Wfc  = (const float*)d_in[2];   // (7, 2048)
  const float* Wq   = (const float*)d_in[3];   // (256, 7)
  const float* Wk   = (const float*)d_in[4];   // (256, 7)
  const float* Wv   = (const float*)d_in[5];   // (256, 7)
  const float* Wo   = (const float*)d_in[6];   // (7, 256)
  const float* ln1g = (const float*)d_in[7];
  const float* ln1b = (const float*)d_in[8];
  const float* W1   = (const float*)d_in[9];   // (64, 7)
  const float* W2   = (const float*)d_in[10];  // (7, 64)
  const float* ln2g = (const float*)d_in[11];
  const float* ln2b = (const float*)d_in[12];
  float* out = (float*)d_out;

  float* AM = (float*)d_ws;              // 392 floats
  float* WT = (float*)d_ws + 512;        // 512*32 floats (swizzled Wfc^T)

  setup_kernel<<<1, 448, 0, stream>>>(Wq, Wk, Wv, Wo, AM);
  wfct_kernel<<<16, 1024, 0, stream>>>(Wfc, WT);
  // feas written into `out` (scratch); attn_kernel rewrites it in place.
  feas_kernel<<<T_FRAMES / FB, 256, 0, stream>>>(lf, WT, out);
  attn_kernel<<<T_FRAMES / BF, 256, 0, stream>>>(
      x, out, AM, W1, W2, ln1g, ln1b, ln2g, ln2b, out);
}

// Round 8
// 243.105 us; speedup vs baseline: 1.3218x; 1.0076x over previous
//
#include <hip/hip_runtime.h>
#include <math.h>

#define T_FRAMES 16384
#define FDIM 2048
#define LQ 30
#define BF 64         // frames per attn block

typedef float f4 __attribute__((ext_vector_type(4)));

// ---------------------------------------------------------------------------
// Kernel 0: precompute per-head 7x7 bilinear forms (unchanged)
// AM layout: [0..195] = A (h*49 + c*7 + c2), [196..391] = M
// ---------------------------------------------------------------------------
__global__ __launch_bounds__(448) void setup_kernel(
    const float* __restrict__ Wq, const float* __restrict__ Wk,
    const float* __restrict__ Wv, const float* __restrict__ Wo,
    float* __restrict__ AM) {
  const int e = threadIdx.x;
  if (e >= 392) return;
  const int which = e / 196;
  const int r = e % 196;
  const int h = r / 49;
  const int rr = r % 49;
  const int c = rr / 7;
  const int c2 = rr % 7;
  float s = 0.0f;
  if (which == 0) {
    for (int d = 0; d < 64; ++d)
      s = fmaf(Wq[(h * 64 + d) * 7 + c], Wk[(h * 64 + d) * 7 + c2], s);
  } else {
    for (int d = 0; d < 64; ++d)
      s = fmaf(Wo[c * 256 + h * 64 + d], Wv[(h * 64 + d) * 7 + c2], s);
  }
  AM[e] = s;
}

// ---------------------------------------------------------------------------
// DPP helper: v += v shuffled by CTRL (VALU-only cross-lane within 16 lanes).
// Standard GCN 16-lane reduce ladder: 0xB1 (xor1), 0x4E (xor2),
// 0x141 (row_half_mirror -> pairs 4-groups), 0x140 (row_mirror -> 8-groups).
// ---------------------------------------------------------------------------
template <int CTRL>
__device__ __forceinline__ float dpp_add(float v) {
  const int s =
      __builtin_amdgcn_update_dpp(0, __float_as_int(v), CTRL, 0xF, 0xF, true);
  return v + __int_as_float(s);
}

// ---------------------------------------------------------------------------
// Kernel 1 (v10): feas = tanh(lf . Wfc^T)
// Barrier-free + MAX TLP. The one untested cell of the design matrix:
// v4's drain-free full-wave-coalesced structure, but at 6 waves/SIMD
// (launch_bounds(256,6), FR=2, unroll 2 to keep ~60 live VGPRs) instead
// of 4. Reduce rebuilt as 4xDPP(VALU) + 2 shuffles (~0.3us vs ~2.5us of
// DS-shuffle drain). lf loads non-temporal (zero reuse; keep L2 for Wfc).
// Zero LDS, zero barriers: nothing blocks wave-interleaving.
// ---------------------------------------------------------------------------
__global__ __launch_bounds__(256, 6) void feas_kernel(
    const float* __restrict__ lf,    // (T, 2048)
    const float* __restrict__ Wfc,   // (7, 2048)
    float* __restrict__ feas) {      // (T, 7)
  const int tid  = threadIdx.x;
  const int lane = tid & 63;
  const int wave = tid >> 6;
  const int t0   = (blockIdx.x * 4 + wave) * 2;   // frames t0, t0+1
  const float* rowp = lf + (size_t)t0 * FDIM + lane * 4;

  float acc0[7] = {0, 0, 0, 0, 0, 0, 0};
  float acc1[7] = {0, 0, 0, 0, 0, 0, 0};

#pragma unroll 2
  for (int ch = 0; ch < 8; ++ch) {
    const f4 a0 = __builtin_nontemporal_load((const f4*)(rowp + ch * 256));
    const f4 a1 = __builtin_nontemporal_load((const f4*)(rowp + FDIM + ch * 256));
#pragma unroll
    for (int c = 0; c < 7; ++c) {
      const f4 w = *(const f4*)(Wfc + c * FDIM + ch * 256 + lane * 4);
      acc0[c] = fmaf(a0.x, w.x, fmaf(a0.y, w.y,
                fmaf(a0.z, w.z, fmaf(a0.w, w.w, acc0[c]))));
      acc1[c] = fmaf(a1.x, w.x, fmaf(a1.y, w.y,
                fmaf(a1.z, w.z, fmaf(a1.w, w.w, acc1[c]))));
    }
  }

  // ---- 64-lane reduce per (frame, channel): 4 DPP + xor16 + xor32 ----
#pragma unroll
  for (int c = 0; c < 7; ++c) {
    float v0 = acc0[c], v1 = acc1[c];
    v0 = dpp_add<0xB1>(v0);   v1 = dpp_add<0xB1>(v1);
    v0 = dpp_add<0x4E>(v0);   v1 = dpp_add<0x4E>(v1);
    v0 = dpp_add<0x141>(v0);  v1 = dpp_add<0x141>(v1);
    v0 = dpp_add<0x140>(v0);  v1 = dpp_add<0x140>(v1);
    v0 += __shfl_xor(v0, 16, 64);  v1 += __shfl_xor(v1, 16, 64);
    v0 += __shfl_xor(v0, 32, 64);  v1 += __shfl_xor(v1, 32, 64);
    acc0[c] = v0;  acc1[c] = v1;
  }

  // lane l < 14 stores channel l%7 of frame t0 + l/7 (contiguous 14 floats)
  float v = acc0[0];
#pragma unroll
  for (int c = 1; c < 7; ++c)
    if (lane == c) v = acc0[c];
#pragma unroll
  for (int c = 0; c < 7; ++c)
    if (lane == 7 + c) v = acc1[c];
  if (lane < 14) feas[(size_t)t0 * 7 + lane] = tanhf(v);
}

// ---------------------------------------------------------------------------
// Kernel 2: attention + FFN + LNs (unchanged -- verified, cheap).
// ---------------------------------------------------------------------------
__global__ __launch_bounds__(256) void attn_kernel(
    const float* __restrict__ x,       // (7, T)
    const float* __restrict__ feas_g,  // (T, 7)  == out
    const float* __restrict__ AM,      // 392
    const float* __restrict__ W1,      // (64, 7)
    const float* __restrict__ W2,      // (7, 64)
    const float* __restrict__ ln1g, const float* __restrict__ ln1b,
    const float* __restrict__ ln2g, const float* __restrict__ ln2b,
    float* __restrict__ out) {         // (T, 7)
  __shared__ float AM_s[392];
  __shared__ float ft[(BF + LQ - 1) * 7];
  __shared__ float feas_s[BF][7];
  __shared__ float hpart[BF][4][7];

  const int tid = threadIdx.x;
  const int t0 = blockIdx.x * BF;

  for (int i = tid; i < 392; i += 256) AM_s[i] = AM[i];
  for (int i = tid; i < (BF + LQ - 1) * 7; i += 256) {
    const int row = i / 7, c = i % 7;
    const int s = t0 - (LQ - 1) + row;
    ft[i] = (s >= 0) ? x[c * T_FRAMES + s] : 0.0f;
  }
  for (int i = tid; i < BF * 7; i += 256)
    feas_s[i / 7][i % 7] = feas_g[(size_t)t0 * 7 + i];
  __syncthreads();

  // ---- phase 2a: (frame, head) per thread, 256/256 active ----
  {
    const int f = tid >> 2;
    const int h = tid & 3;
    float fe[7];
#pragma unroll
    for (int c = 0; c < 7; ++c) fe[c] = feas_s[f][c];

    const float* Ah = AM_s + h * 49;
    const float* Mh = AM_s + 196 + h * 49;
    float qk[7];
#pragma unroll
    for (int c2 = 0; c2 < 7; ++c2) {
      float s = 0.0f;
#pragma unroll
      for (int c = 0; c < 7; ++c) s = fmaf(fe[c], Ah[c * 7 + c2], s);
      qk[c2] = s * 0.125f;
    }
    const float* frow = &ft[f * 7];
    float sc[LQ];
    float m = -1e30f;
#pragma unroll
    for (int j = 0; j < LQ; ++j) {
      const float* r = frow + j * 7;
      float s = 0.0f;
#pragma unroll
      for (int c2 = 0; c2 < 7; ++c2) s = fmaf(qk[c2], r[c2], s);
      sc[j] = s;
      m = fmaxf(m, s);
    }
    float sum = 0.0f;
    float wsum[7] = {0, 0, 0, 0, 0, 0, 0};
#pragma unroll
    for (int j = 0; j < LQ; ++j) {
      const float p = __expf(sc[j] - m);
      sum += p;
      const float* r = frow + j * 7;
#pragma unroll
      for (int c2 = 0; c2 < 7; ++c2) wsum[c2] = fmaf(p, r[c2], wsum[c2]);
    }
    const float inv = 1.0f / sum;
#pragma unroll
    for (int c = 0; c < 7; ++c) {
      float s = 0.0f;
#pragma unroll
      for (int c2 = 0; c2 < 7; ++c2) s = fmaf(Mh[c * 7 + c2], wsum[c2], s);
      hpart[f][h][c] = s * inv;
    }
  }
  __syncthreads();

  // ---- phase 2b: per-frame epilogue ----
  if (tid < BF) {
    const int f = tid;
    float v[7];
#pragma unroll
    for (int c = 0; c < 7; ++c)
      v[c] = feas_s[f][c] + hpart[f][0][c] + hpart[f][1][c] + hpart[f][2][c] + hpart[f][3][c];

    float mu = 0.0f;
#pragma unroll
    for (int c = 0; c < 7; ++c) mu += v[c];
    mu *= (1.0f / 7.0f);
    float var = 0.0f;
#pragma unroll
    for (int c = 0; c < 7; ++c) { const float d = v[c] - mu; var = fmaf(d, d, var); }
    var *= (1.0f / 7.0f);
    float rs = rsqrtf(var + 1e-5f);
    float o1[7];
#pragma unroll
    for (int c = 0; c < 7; ++c) o1[c] = (v[c] - mu) * rs * ln1g[c] + ln1b[c];

    float ff[7] = {0, 0, 0, 0, 0, 0, 0};
    for (int k = 0; k < 64; ++k) {
      float hk = 0.0f;
#pragma unroll
      for (int c = 0; c < 7; ++c) hk = fmaf(W1[k * 7 + c], o1[c], hk);
      hk = fmaxf(hk, 0.0f);
#pragma unroll
      for (int c = 0; c < 7; ++c) ff[c] = fmaf(W2[c * 64 + k], hk, ff[c]);
    }

#pragma unroll
    for (int c = 0; c < 7; ++c) v[c] = ff[c] + o1[c];
    mu = 0.0f;
#pragma unroll
    for (int c = 0; c < 7; ++c) mu += v[c];
    mu *= (1.0f / 7.0f);
    var = 0.0f;
#pragma unroll
    for (int c = 0; c < 7; ++c) { const float d = v[c] - mu; var = fmaf(d, d, var); }
    var *= (1.0f / 7.0f);
    rs = rsqrtf(var + 1e-5f);
    const int t = t0 + f;
#pragma unroll
    for (int c = 0; c < 7; ++c)
      out[(size_t)t * 7 + c] = (v[c] - mu) * rs * ln2g[c] + ln2b[c];
  }
}

// ---------------------------------------------------------------------------
extern "C" void kernel_launch(void* const* d_in, const int* in_sizes, int n_in,
                              void* d_out, int out_size, void* d_ws, size_t ws_size,
                              hipStream_t stream) {
  const float* x    = (const float*)d_in[0];   // (1, 7, T)
  const float* lf   = (const float*)d_in[1];   // (1, T, 2048)
  const float* Wfc  = (const float*)d_in[2];   // (7, 2048)
  const float* Wq   = (const float*)d_in[3];   // (256, 7)
  const float* Wk   = (const float*)d_in[4];   // (256, 7)
  const float* Wv   = (const float*)d_in[5];   // (256, 7)
  const float* Wo   = (const float*)d_in[6];   // (7, 256)
  const float* ln1g = (const float*)d_in[7];
  const float* ln1b = (const float*)d_in[8];
  const float* W1   = (const float*)d_in[9];   // (64, 7)
  const float* W2   = (const float*)d_in[10];  // (7, 64)
  const float* ln2g = (const float*)d_in[11];
  const float* ln2b = (const float*)d_in[12];
  float* out = (float*)d_out;

  float* AM = (float*)d_ws;   // 392 floats

  setup_kernel<<<1, 448, 0, stream>>>(Wq, Wk, Wv, Wo, AM);
  // feas written into `out` (scratch); attn_kernel rewrites it in place.
  feas_kernel<<<T_FRAMES / 8, 256, 0, stream>>>(lf, Wfc, out);
  attn_kernel<<<T_FRAMES / BF, 256, 0, stream>>>(
      x, out, AM, W1, W2, ln1g, ln1b, ln2g, ln2b, out);
}